// Round 10
// baseline (112.465 us; speedup 1.0000x reference)
//
#include <hip/hip_runtime.h>
#include <math.h>

// Problem constants (from reference)
#define BB     8192      // batch
#define DD     512       // embed dim
#define NEXP   16        // expansions per sample
#define TOPK   2048      // round(B * 0.25)
#define AUGX_ROWS (BB + TOPK * NEXP)              // 40960
#define AUGT_OFF  ((size_t)AUGX_ROWS * DD)        // 20971520
#define ISEXP_OFF (AUGT_OFF + AUGX_ROWS)          // 21012480

#define JCHUNK 256       // j-scores per rank block
#define COPY_BLOCKS 1024 // copy blocks fused into emit launch (256 thr each)
#define BMP 520          // bf16 row pitch: 1040 B = 16B-aligned, bank step 4
#define GSTRIDE 328      // floats per sample in gbuf: 324 G + 4 header
#define CSTRIDE 288      // floats per sample in cbuf: [18][16] transposed

typedef __attribute__((ext_vector_type(8)))  short bf16x8;
typedef __attribute__((ext_vector_type(16))) float f32x16;

__device__ inline ushort f2bf(float f) {   // RNE f32 -> bf16 bits
    uint u = __builtin_bit_cast(uint, f);
    return (ushort)((u + 0x7FFFu + ((u >> 16) & 1u)) >> 16);
}

// ---------------------------------------------------------------------------
// Kernel 1: per-sample score in f64 (matches harness ordering at ties)
__global__ __launch_bounds__(64) void score_kernel(
    const float* __restrict__ x, const int* __restrict__ y,
    const float* __restrict__ prox, double* __restrict__ scores)
{
    int i = blockIdx.x;
    int lane = threadIdx.x;
    const float* xr = x + (size_t)i * DD;
    const float* pr = prox + (size_t)y[i] * DD;
    double sx = 0.0, sp = 0.0, dp = 0.0;
    #pragma unroll
    for (int e = 0; e < DD; e += 64) {
        float xv = xr[e + lane];
        float pv = pr[e + lane];
        sx += (double)xv * (double)xv;
        sp += (double)pv * (double)pv;
        dp += (double)xv * (double)pv;
    }
    #pragma unroll
    for (int off = 32; off > 0; off >>= 1) {
        sx += __shfl_down(sx, off);
        sp += __shfl_down(sp, off);
        dp += __shfl_down(dp, off);
    }
    if (lane == 0) {
        scores[i] = dp / (sqrt(sx + 1e-12) * sqrt(sp + 1e-12));
    }
}

// ---------------------------------------------------------------------------
// Kernel 2: partial rank accumulation; tie-break = jax.lax.top_k stability.
// Integer atomics only (exact, order-independent).
__global__ __launch_bounds__(256) void rank_kernel(
    const double* __restrict__ scores, int* __restrict__ ranks)
{
    __shared__ double ch[JCHUNK];
    int i = blockIdx.x * 256 + threadIdx.x;
    int jbase = blockIdx.y * JCHUNK;
    double si = scores[i];
    if (threadIdx.x < JCHUNK) ch[threadIdx.x] = scores[jbase + threadIdx.x];
    __syncthreads();
    int rank = 0;
    #pragma unroll 8
    for (int j = 0; j < JCHUNK; ++j) {
        double sj = ch[j];
        int jj = jbase + j;
        rank += (sj > si || (sj == si && jj < i)) ? 1 : 0;
    }
    atomicAdd(&ranks[i], rank);
}

// ---------------------------------------------------------------------------
// Kernel 3: ordered compaction (ascending sel[]), write is_expan floats.
__global__ __launch_bounds__(256) void compact_kernel(
    const int* __restrict__ ranks, int* __restrict__ sel, float* __restrict__ out)
{
    __shared__ int wsum[4];
    int t = threadIdx.x;
    int base = t * 32;
    int fl[32];
    int cnt = 0;
    for (int k = 0; k < 32; ++k) {
        fl[k] = (ranks[base + k] < TOPK) ? 1 : 0;
        cnt += fl[k];
    }
    int lane = t & 63, wave = t >> 6;
    int inc = cnt;
    #pragma unroll
    for (int off = 1; off < 64; off <<= 1) {
        int n = __shfl_up(inc, off);
        if (lane >= off) inc += n;
    }
    if (lane == 63) wsum[wave] = inc;
    __syncthreads();
    int wbase = 0;
    for (int w = 0; w < wave; ++w) wbase += wsum[w];
    int pos = wbase + inc - cnt;
    for (int k = 0; k < 32; ++k) {
        int i = base + k;
        out[ISEXP_OFF + i] = fl[k] ? 1.0f : 0.0f;
        if (fl[k]) sel[pos++] = i;
    }
}

// ---------------------------------------------------------------------------
__device__ inline void block_sum3(float& a, float& b, float& c, float* red, int t)
{
    #pragma unroll
    for (int off = 32; off > 0; off >>= 1) {
        a += __shfl_down(a, off);
        b += __shfl_down(b, off);
        c += __shfl_down(c, off);
    }
    __syncthreads();
    if ((t & 63) == 0) { int w = t >> 6; red[w] = a; red[4 + w] = b; red[8 + w] = c; }
    __syncthreads();
    a = red[0] + red[1] + red[2] + red[3];
    b = red[4] + red[5] + red[6] + red[7];
    c = red[8] + red[9] + red[10] + red[11];
}

// ---------------------------------------------------------------------------
// Kernel 4 (gram): per selected sample, 4-wave MFMA Gram of the 18-vector
// bf16 basis [w, u1, r0..r15]; deterministic LDS tree reduce (no atomics).
// Writes G[18][18] + header {xn, pn, zw, r1n} to ws.
__global__ __launch_bounds__(256) void gram_kernel(
    const float* __restrict__ x, const int* __restrict__ y,
    const float* __restrict__ prox, const float* __restrict__ rands,
    const int* __restrict__ sel, float* __restrict__ gbuf)
{
    __shared__ ushort Bm[18][BMP];   // 18720 B
    __shared__ float Gp[4][18][19];  //  5472 B
    __shared__ float red[12];

    const int j = blockIdx.x, t = threadIdx.x;
    const int wave = t >> 6, lane = t & 63;
    const int s = sel[j];
    const int cls = y[s];

    // stage 16 rand rows into LDS as bf16 (transient registers only)
    {
        const float* rbase = rands + (size_t)j * NEXP * DD;
        #pragma unroll
        for (int i = 0; i < 8; ++i) {
            int row = 2 * i + (t >> 7);
            int col = (t & 127) * 4;
            float4 vv = *(const float4*)(rbase + (size_t)row * DD + col);
            ushort4 bv = { f2bf(vv.x), f2bf(vv.y), f2bf(vv.z), f2bf(vv.w) };
            *(ushort4*)&Bm[2 + row][col] = bv;
        }
    }

    float2 xv = ((const float2*)(x + (size_t)s * DD))[t];
    float2 pv = ((const float2*)(prox + (size_t)cls * DD))[t];

    float sx  = xv.x * xv.x + xv.y * xv.y;
    float sp  = pv.x * pv.x + pv.y * pv.y;
    float dxp = xv.x * pv.x + xv.y * pv.y;
    block_sum3(sx, sp, dxp, red, t);

    float xn = sqrtf(sx + 1e-12f), pn = sqrtf(sp + 1e-12f);
    float2 z  = { xv.x / xn, xv.y / xn };
    float2 w  = { pv.x / pn, pv.y / pn };
    float zw  = dxp / (xn * pn);
    float2 M  = { zw * w.x, zw * w.y };
    float2 r1 = { z.x - M.x, z.y - M.y };
    float r1sq = fmaxf(1.0f - zw * zw, 1e-12f);  // |r1|^2 = 1 - zw^2 (unit z,w)
    float r1n = sqrtf(r1sq);
    float inv1 = 1.0f / r1n;
    float2 u1 = { r1.x * inv1, r1.y * inv1 };

    { ushort2 wb = { f2bf(w.x),  f2bf(w.y)  }; *(ushort2*)&Bm[0][2 * t] = wb; }
    { ushort2 ub = { f2bf(u1.x), f2bf(u1.y) }; *(ushort2*)&Bm[1][2 * t] = ub; }
    __syncthreads();

    // 4-wave MFMA: wave covers K-slice [wave*128, wave*128+128).
    // A-frag == B-frag (G = B.B^T): lane row = lane&31 (clamped),
    // k = kw + stp*16 + (lane>>5)*8 + i.
    {
        int row = lane & 31; if (row > 17) row = 17;
        int koff = (lane >> 5) * 8;
        const int kw = wave * 128;
        f32x16 acc = {0,0,0,0,0,0,0,0,0,0,0,0,0,0,0,0};
        #pragma unroll
        for (int stp = 0; stp < 8; ++stp) {
            bf16x8 av = *(const bf16x8*)&Bm[row][kw + stp * 16 + koff];
            acc = __builtin_amdgcn_mfma_f32_32x32x16_bf16(av, av, acc, 0, 0, 0);
        }
        // D layout: col = lane&31, row = (reg&3) + 8*(reg>>2) + 4*(lane>>5)
        int col = lane & 31;
        if (col < 18) {
            #pragma unroll
            for (int rg = 0; rg < 16; ++rg) {
                int rr = (rg & 3) + 8 * (rg >> 2) + 4 * (lane >> 5);
                if (rr < 18) Gp[wave][rr][col] = acc[rg];
            }
        }
    }
    __syncthreads();

    // deterministic tree reduce of 4 wave partials -> global G
    float* gout = gbuf + (size_t)j * GSTRIDE;
    for (int e = t; e < 324; e += 256) {
        int r = e / 18, c = e - r * 18;
        gout[e] = (Gp[0][r][c] + Gp[1][r][c]) + (Gp[2][r][c] + Gp[3][r][c]);
    }
    if (t == 0) {
        float4 h = { xn, pn, zw, r1n };
        *(float4*)(gout + 324) = h;
    }
}

// ---------------------------------------------------------------------------
// Kernel 5 (solve): one independent WAVE per sample. Register right-looking
// Cholesky (shuffle broadcasts), then 16 back-solves C = bw_ext @ L^-1.
// Writes C transposed [18][16] for vectorized broadcast reads in emit.
__global__ __launch_bounds__(256) void solve_kernel(
    const float* __restrict__ gbuf, const float* __restrict__ bwg,
    float* __restrict__ cbuf)
{
    __shared__ float Ls[4][18][19];  // per-wave L scratch
    __shared__ float bws[272];       // bweights rows 1..16

    const int t = threadIdx.x, wave = t >> 6, lane = t & 63;
    for (int k = t; k < 272; k += 256) bws[k] = bwg[17 + k];
    __syncthreads();

    const int j = blockIdx.x * 4 + wave;
    const float* gs = gbuf + (size_t)j * GSTRIDE;
    const int jl = (lane < 18) ? lane : 17;   // lanes >=18 duplicate row 17

    float Greg[18];
    #pragma unroll
    for (int c = 0; c < 18; ++c) Greg[c] = gs[jl * 18 + c];

    float Lrow[18], invd[18];
    #pragma unroll
    for (int col = 0; col < 18; ++col) {
        float pivot = __shfl(Greg[col], col);   // fully-updated diagonal
        float rsq = rsqrtf(pivot);
        invd[col] = rsq;                        // identical on all lanes
        float lv = (jl >= col) ? Greg[col] * rsq : 0.0f;
        Lrow[col] = lv;
        #pragma unroll
        for (int c = col + 1; c < 18; ++c) {    // Schur update
            float lc = __shfl(lv, c);           // L[c][col]
            Greg[c] -= lv * lc;
        }
    }
    #pragma unroll
    for (int c = 0; c < 18; ++c) Ls[wave][jl][c] = Lrow[c];

    // back-substitution on lanes 0..15: solve L^T c = bw_ext_r (r = lane).
    // Same-wave LDS RAW (write above, cross-lane read below) is in-order.
    if (lane < 16) {
        float b[18];
        b[0] = 0.0f;
        #pragma unroll
        for (int m = 1; m < 18; ++m) b[m] = bws[lane * 17 + (m - 1)];
        float* co = cbuf + (size_t)j * CSTRIDE;
        #pragma unroll
        for (int k = 17; k >= 0; --k) {
            float xk = b[k] * invd[k];
            co[k * 16 + lane] = xk;             // CsT[k][r]
            #pragma unroll
            for (int m = 0; m < k; ++m)
                b[m] -= Ls[wave][k][m] * xk;    // broadcast reads of row k
        }
    }
}

// ---------------------------------------------------------------------------
// Kernel 6 (emit): blocks 0..TOPK-1 stream one sample's 16 output rows
// (zero serial work, rands re-read is L2/L3-resident); blocks >= TOPK copy x.
// 256 threads; thread owns 2 dims (float2) -> 32 accumulator VGPRs.
__global__ __launch_bounds__(256) void emit_kernel(
    const float* __restrict__ x, const int* __restrict__ y,
    const float* __restrict__ prox, const float* __restrict__ rands,
    const int* __restrict__ sel, const float* __restrict__ gbuf,
    const float* __restrict__ cbuf, float* __restrict__ out)
{
    const int t = threadIdx.x;

    if (blockIdx.x >= TOPK) {  // fused copy: aug_x[0:B] = x, aug_t[0:B] = y
        int tid = (blockIdx.x - TOPK) * 256 + t;
        const float4* src = (const float4*)x;
        float4* dst = (float4*)out;
        const int nvec = BB * DD / 4;
        for (int idx = tid; idx < nvec; idx += COPY_BLOCKS * 256) dst[idx] = src[idx];
        for (int i = tid; i < BB; i += COPY_BLOCKS * 256) out[AUGT_OFF + i] = (float)y[i];
        return;
    }

    __shared__ float CsT[18][16];    // C transposed, rows 64 B

    const int j = blockIdx.x;
    const float* co = cbuf + (size_t)j * CSTRIDE;
    for (int e = t; e < 288; e += 256) ((float*)CsT)[e] = co[e];

    const int s = sel[j];
    const int cls = y[s];
    float4 h = *(const float4*)(gbuf + (size_t)j * GSTRIDE + 324);
    const float xn = h.x, pn = h.y, zw = h.z, r1n = h.w;

    float2 xv = ((const float2*)(x + (size_t)s * DD))[t];
    float2 pv = ((const float2*)(prox + (size_t)cls * DD))[t];
    const float ixn = 1.0f / xn, ipn = 1.0f / pn, ir1 = 1.0f / r1n;
    float2 wv = { pv.x * ipn, pv.y * ipn };
    float2 zv = { xv.x * ixn, xv.y * ixn };
    float2 Mv = { zw * wv.x, zw * wv.y };
    float2 uv = { (zv.x - Mv.x) * ir1, (zv.y - Mv.y) * ir1 };
    __syncthreads();

    float a0[16], a1[16];
    #pragma unroll
    for (int q = 0; q < 4; ++q) {
        float4 cw = *(const float4*)&CsT[0][q * 4];   // C[r][0] (broadcast)
        float4 cu = *(const float4*)&CsT[1][q * 4];   // C[r][1]
        #pragma unroll
        for (int i = 0; i < 4; ++i) {
            float w_ = ((const float*)&cw)[i], u_ = ((const float*)&cu)[i];
            a0[q * 4 + i] = w_ * wv.x + u_ * uv.x;
            a1[q * 4 + i] = w_ * wv.y + u_ * uv.y;
        }
    }

    const float* rbase = rands + (size_t)j * NEXP * DD;
    #pragma unroll
    for (int k = 0; k < NEXP; ++k) {
        float2 rv = ((const float2*)(rbase + (size_t)k * DD))[t];
        #pragma unroll
        for (int q = 0; q < 4; ++q) {
            float4 cc = *(const float4*)&CsT[2 + k][q * 4];  // broadcast b128
            #pragma unroll
            for (int i = 0; i < 4; ++i) {
                float c_ = ((const float*)&cc)[i];
                a0[q * 4 + i] += c_ * rv.x;
                a1[q * 4 + i] += c_ * rv.y;
            }
        }
    }

    float* orow = out + ((size_t)BB + (size_t)j * NEXP) * DD;
    #pragma unroll
    for (int r = 0; r < 16; ++r) {
        float2 ov = { Mv.x + r1n * a0[r], Mv.y + r1n * a1[r] };
        ((float2*)(orow + (size_t)r * DD))[t] = ov;
    }

    if (t < NEXP) out[AUGT_OFF + BB + (size_t)j * NEXP + t] = (float)cls;
}

// ---------------------------------------------------------------------------
extern "C" void kernel_launch(void* const* d_in, const int* in_sizes, int n_in,
                              void* d_out, int out_size, void* d_ws, size_t ws_size,
                              hipStream_t stream)
{
    const float* x     = (const float*)d_in[0];   // [8192,512]
    const int*   y     = (const int*)d_in[1];     // [8192]
    const float* prox  = (const float*)d_in[2];   // [11318,512]
    const float* bw    = (const float*)d_in[3];   // [17,17]
    const float* rands = (const float*)d_in[4];   // [2048,16,512]
    float* out = (float*)d_out;

    char* wsb = (char*)d_ws;
    double* scores = (double*)wsb;                            // 64 KB
    int* ranks = (int*)(wsb + 65536);                         // 32 KB
    int* sel   = (int*)(wsb + 65536 + 32768);                 // 8 KB
    float* gbuf = (float*)(wsb + 114688);                     // 2048*1312 B = 2.56 MB
    float* cbuf = (float*)(wsb + 114688 + (size_t)TOPK * GSTRIDE * 4); // 2.25 MB

    hipMemsetAsync(ranks, 0, BB * sizeof(int), stream);

    score_kernel<<<BB, 64, 0, stream>>>(x, y, prox, scores);
    dim3 rgrid(BB / 256, BB / JCHUNK);
    rank_kernel<<<rgrid, 256, 0, stream>>>(scores, ranks);
    compact_kernel<<<1, 256, 0, stream>>>(ranks, sel, out);
    gram_kernel<<<TOPK, 256, 0, stream>>>(x, y, prox, rands, sel, gbuf);
    solve_kernel<<<TOPK / 4, 256, 0, stream>>>(gbuf, bw, cbuf);
    emit_kernel<<<TOPK + COPY_BLOCKS, 256, 0, stream>>>(x, y, prox, rands, sel,
                                                        gbuf, cbuf, out);
}

// Round 11
// 94.764 us; speedup vs baseline: 1.1868x; 1.1868x over previous
//
#include <hip/hip_runtime.h>
#include <math.h>

// Problem constants (from reference)
#define BB     8192      // batch
#define DD     512       // embed dim
#define NEXP   16        // expansions per sample
#define TOPK   2048      // round(B * 0.25)
#define AUGX_ROWS (BB + TOPK * NEXP)              // 40960
#define AUGT_OFF  ((size_t)AUGX_ROWS * DD)        // 20971520
#define ISEXP_OFF (AUGT_OFF + AUGX_ROWS)          // 21012480

#define JCHUNK 256       // j-scores per rank block
#define COPY_BLOCKS 1024 // copy blocks fused into emit launch (256 thr each)
#define BMP 520          // bf16 row pitch: 1040 B = 16B-aligned, bank step 4
#define GSTRIDE 328      // floats per sample in gbuf: 324 G + 4 header
#define CSTRIDE 288      // floats per sample in cbuf: [18][16] transposed

typedef __attribute__((ext_vector_type(8)))  short bf16x8;
typedef __attribute__((ext_vector_type(16))) float f32x16;

__device__ inline ushort f2bf(float f) {   // RNE f32 -> bf16 bits
    uint u = __builtin_bit_cast(uint, f);
    return (ushort)((u + 0x7FFFu + ((u >> 16) & 1u)) >> 16);
}

// ---------------------------------------------------------------------------
// Kernel 1: per-sample score in f64 (matches harness ordering at ties)
__global__ __launch_bounds__(64) void score_kernel(
    const float* __restrict__ x, const int* __restrict__ y,
    const float* __restrict__ prox, double* __restrict__ scores)
{
    int i = blockIdx.x;
    int lane = threadIdx.x;
    const float* xr = x + (size_t)i * DD;
    const float* pr = prox + (size_t)y[i] * DD;
    double sx = 0.0, sp = 0.0, dp = 0.0;
    #pragma unroll
    for (int e = 0; e < DD; e += 64) {
        float xv = xr[e + lane];
        float pv = pr[e + lane];
        sx += (double)xv * (double)xv;
        sp += (double)pv * (double)pv;
        dp += (double)xv * (double)pv;
    }
    #pragma unroll
    for (int off = 32; off > 0; off >>= 1) {
        sx += __shfl_down(sx, off);
        sp += __shfl_down(sp, off);
        dp += __shfl_down(dp, off);
    }
    if (lane == 0) {
        scores[i] = dp / (sqrt(sx + 1e-12) * sqrt(sp + 1e-12));
    }
}

// ---------------------------------------------------------------------------
// Kernel 2: partial rank accumulation; tie-break = jax.lax.top_k stability.
// Integer atomics only (exact, order-independent).
__global__ __launch_bounds__(256) void rank_kernel(
    const double* __restrict__ scores, int* __restrict__ ranks)
{
    __shared__ double ch[JCHUNK];
    int i = blockIdx.x * 256 + threadIdx.x;
    int jbase = blockIdx.y * JCHUNK;
    double si = scores[i];
    if (threadIdx.x < JCHUNK) ch[threadIdx.x] = scores[jbase + threadIdx.x];
    __syncthreads();
    int rank = 0;
    #pragma unroll 8
    for (int j = 0; j < JCHUNK; ++j) {
        double sj = ch[j];
        int jj = jbase + j;
        rank += (sj > si || (sj == si && jj < i)) ? 1 : 0;
    }
    atomicAdd(&ranks[i], rank);
}

// ---------------------------------------------------------------------------
// Kernel 3: ordered compaction (ascending sel[]), write is_expan floats.
__global__ __launch_bounds__(256) void compact_kernel(
    const int* __restrict__ ranks, int* __restrict__ sel, float* __restrict__ out)
{
    __shared__ int wsum[4];
    int t = threadIdx.x;
    int base = t * 32;
    int fl[32];
    int cnt = 0;
    for (int k = 0; k < 32; ++k) {
        fl[k] = (ranks[base + k] < TOPK) ? 1 : 0;
        cnt += fl[k];
    }
    int lane = t & 63, wave = t >> 6;
    int inc = cnt;
    #pragma unroll
    for (int off = 1; off < 64; off <<= 1) {
        int n = __shfl_up(inc, off);
        if (lane >= off) inc += n;
    }
    if (lane == 63) wsum[wave] = inc;
    __syncthreads();
    int wbase = 0;
    for (int w = 0; w < wave; ++w) wbase += wsum[w];
    int pos = wbase + inc - cnt;
    for (int k = 0; k < 32; ++k) {
        int i = base + k;
        out[ISEXP_OFF + i] = fl[k] ? 1.0f : 0.0f;
        if (fl[k]) sel[pos++] = i;
    }
}

// ---------------------------------------------------------------------------
__device__ inline void block_sum3(float& a, float& b, float& c, float* red, int t)
{
    #pragma unroll
    for (int off = 32; off > 0; off >>= 1) {
        a += __shfl_down(a, off);
        b += __shfl_down(b, off);
        c += __shfl_down(c, off);
    }
    __syncthreads();
    if ((t & 63) == 0) { int w = t >> 6; red[w] = a; red[4 + w] = b; red[8 + w] = c; }
    __syncthreads();
    a = red[0] + red[1] + red[2] + red[3];
    b = red[4] + red[5] + red[6] + red[7];
    c = red[8] + red[9] + red[10] + red[11];
}

// ---------------------------------------------------------------------------
// Kernel 4 (gram): per selected sample, 4-wave MFMA Gram of the 18-vector
// bf16 basis [w, u1, r0..r15]; deterministic LDS tree reduce (no atomics).
// Writes G[18][18] + header {xn, pn, zw, r1n} to ws.
__global__ __launch_bounds__(256) void gram_kernel(
    const float* __restrict__ x, const int* __restrict__ y,
    const float* __restrict__ prox, const float* __restrict__ rands,
    const int* __restrict__ sel, float* __restrict__ gbuf)
{
    __shared__ ushort Bm[18][BMP];   // 18720 B
    __shared__ float Gp[4][18][19];  //  5472 B
    __shared__ float red[12];

    const int j = blockIdx.x, t = threadIdx.x;
    const int wave = t >> 6, lane = t & 63;
    const int s = sel[j];
    const int cls = y[s];

    // stage 16 rand rows into LDS as bf16 (transient registers only)
    {
        const float* rbase = rands + (size_t)j * NEXP * DD;
        #pragma unroll
        for (int i = 0; i < 8; ++i) {
            int row = 2 * i + (t >> 7);
            int col = (t & 127) * 4;
            float4 vv = *(const float4*)(rbase + (size_t)row * DD + col);
            ushort4 bv = { f2bf(vv.x), f2bf(vv.y), f2bf(vv.z), f2bf(vv.w) };
            *(ushort4*)&Bm[2 + row][col] = bv;
        }
    }

    float2 xv = ((const float2*)(x + (size_t)s * DD))[t];
    float2 pv = ((const float2*)(prox + (size_t)cls * DD))[t];

    float sx  = xv.x * xv.x + xv.y * xv.y;
    float sp  = pv.x * pv.x + pv.y * pv.y;
    float dxp = xv.x * pv.x + xv.y * pv.y;
    block_sum3(sx, sp, dxp, red, t);

    float xn = sqrtf(sx + 1e-12f), pn = sqrtf(sp + 1e-12f);
    float2 z  = { xv.x / xn, xv.y / xn };
    float2 w  = { pv.x / pn, pv.y / pn };
    float zw  = dxp / (xn * pn);
    float2 M  = { zw * w.x, zw * w.y };
    float2 r1 = { z.x - M.x, z.y - M.y };
    float r1sq = fmaxf(1.0f - zw * zw, 1e-12f);  // |r1|^2 = 1 - zw^2 (unit z,w)
    float r1n = sqrtf(r1sq);
    float inv1 = 1.0f / r1n;
    float2 u1 = { r1.x * inv1, r1.y * inv1 };

    { ushort2 wb = { f2bf(w.x),  f2bf(w.y)  }; *(ushort2*)&Bm[0][2 * t] = wb; }
    { ushort2 ub = { f2bf(u1.x), f2bf(u1.y) }; *(ushort2*)&Bm[1][2 * t] = ub; }
    __syncthreads();

    // 4-wave MFMA: wave covers K-slice [wave*128, wave*128+128).
    // A-frag == B-frag (G = B.B^T): lane row = lane&31 (clamped),
    // k = kw + stp*16 + (lane>>5)*8 + i.
    {
        int row = lane & 31; if (row > 17) row = 17;
        int koff = (lane >> 5) * 8;
        const int kw = wave * 128;
        f32x16 acc = {0,0,0,0,0,0,0,0,0,0,0,0,0,0,0,0};
        #pragma unroll
        for (int stp = 0; stp < 8; ++stp) {
            bf16x8 av = *(const bf16x8*)&Bm[row][kw + stp * 16 + koff];
            acc = __builtin_amdgcn_mfma_f32_32x32x16_bf16(av, av, acc, 0, 0, 0);
        }
        // D layout: col = lane&31, row = (reg&3) + 8*(reg>>2) + 4*(lane>>5)
        int col = lane & 31;
        if (col < 18) {
            #pragma unroll
            for (int rg = 0; rg < 16; ++rg) {
                int rr = (rg & 3) + 8 * (rg >> 2) + 4 * (lane >> 5);
                if (rr < 18) Gp[wave][rr][col] = acc[rg];
            }
        }
    }
    __syncthreads();

    // deterministic tree reduce of 4 wave partials -> global G
    float* gout = gbuf + (size_t)j * GSTRIDE;
    for (int e = t; e < 324; e += 256) {
        int r = e / 18, c = e - r * 18;
        gout[e] = (Gp[0][r][c] + Gp[1][r][c]) + (Gp[2][r][c] + Gp[3][r][c]);
    }
    if (t == 0) {
        float4 h = { xn, pn, zw, r1n };
        *(float4*)(gout + 324) = h;
    }
}

// ---------------------------------------------------------------------------
// Kernel 5 (solve): one independent WAVE per sample. Register right-looking
// Cholesky (shuffle broadcasts), then 16 back-solves C = bw_ext @ L^-1.
// Writes C transposed [18][16] for vectorized broadcast reads in emit.
__global__ __launch_bounds__(256) void solve_kernel(
    const float* __restrict__ gbuf, const float* __restrict__ bwg,
    float* __restrict__ cbuf)
{
    __shared__ float Ls[4][18][19];  // per-wave L scratch
    __shared__ float bws[272];       // bweights rows 1..16

    const int t = threadIdx.x, wave = t >> 6, lane = t & 63;
    for (int k = t; k < 272; k += 256) bws[k] = bwg[17 + k];
    __syncthreads();

    const int j = blockIdx.x * 4 + wave;
    const float* gs = gbuf + (size_t)j * GSTRIDE;
    const int jl = (lane < 18) ? lane : 17;   // lanes >=18 duplicate row 17

    float Greg[18];
    #pragma unroll
    for (int c = 0; c < 18; ++c) Greg[c] = gs[jl * 18 + c];

    float Lrow[18], invd[18];
    #pragma unroll
    for (int col = 0; col < 18; ++col) {
        float pivot = __shfl(Greg[col], col);   // fully-updated diagonal
        float rsq = rsqrtf(pivot);
        invd[col] = rsq;                        // identical on all lanes
        float lv = (jl >= col) ? Greg[col] * rsq : 0.0f;
        Lrow[col] = lv;
        #pragma unroll
        for (int c = col + 1; c < 18; ++c) {    // Schur update
            float lc = __shfl(lv, c);           // L[c][col]
            Greg[c] -= lv * lc;
        }
    }
    #pragma unroll
    for (int c = 0; c < 18; ++c) Ls[wave][jl][c] = Lrow[c];

    // back-substitution on lanes 0..15: solve L^T c = bw_ext_r (r = lane).
    // Same-wave LDS RAW (write above, cross-lane read below) is in-order.
    if (lane < 16) {
        float b[18];
        b[0] = 0.0f;
        #pragma unroll
        for (int m = 1; m < 18; ++m) b[m] = bws[lane * 17 + (m - 1)];
        float* co = cbuf + (size_t)j * CSTRIDE;
        #pragma unroll
        for (int k = 17; k >= 0; --k) {
            float xk = b[k] * invd[k];
            co[k * 16 + lane] = xk;             // CsT[k][r]
            #pragma unroll
            for (int m = 0; m < k; ++m)
                b[m] -= Ls[wave][k][m] * xk;    // broadcast reads of row k
        }
    }
}

// ---------------------------------------------------------------------------
// Kernel 6 (emit): blocks 0..TOPK-1 stream one sample's 16 output rows
// (zero serial work, rands re-read is L2/L3-resident); blocks >= TOPK copy x.
// 256 threads; thread owns 2 dims. __launch_bounds__(256,6) caps VGPR at ~84
// and #pragma unroll 4 limits in-flight loads (R10: full unroll -> 180 VGPR,
// 10% occupancy, latency-bound at 70us).
__global__ __launch_bounds__(256, 6) void emit_kernel(
    const float* __restrict__ x, const int* __restrict__ y,
    const float* __restrict__ prox, const float* __restrict__ rands,
    const int* __restrict__ sel, const float* __restrict__ gbuf,
    const float* __restrict__ cbuf, float* __restrict__ out)
{
    const int t = threadIdx.x;

    if (blockIdx.x >= TOPK) {  // fused copy: aug_x[0:B] = x, aug_t[0:B] = y
        int tid = (blockIdx.x - TOPK) * 256 + t;
        const float4* src = (const float4*)x;
        float4* dst = (float4*)out;
        const int nvec = BB * DD / 4;
        for (int idx = tid; idx < nvec; idx += COPY_BLOCKS * 256) dst[idx] = src[idx];
        for (int i = tid; i < BB; i += COPY_BLOCKS * 256) out[AUGT_OFF + i] = (float)y[i];
        return;
    }

    __shared__ float CsT[18][16];    // C transposed, rows 64 B

    const int j = blockIdx.x;
    const float* co = cbuf + (size_t)j * CSTRIDE;
    for (int e = t; e < 288; e += 256) ((float*)CsT)[e] = co[e];

    const int s = sel[j];
    const int cls = y[s];
    float4 h = *(const float4*)(gbuf + (size_t)j * GSTRIDE + 324);
    const float xn = h.x, pn = h.y, zw = h.z, r1n = h.w;

    float2 xv = ((const float2*)(x + (size_t)s * DD))[t];
    float2 pv = ((const float2*)(prox + (size_t)cls * DD))[t];
    const float ixn = 1.0f / xn, ipn = 1.0f / pn, ir1 = 1.0f / r1n;
    float2 wv = { pv.x * ipn, pv.y * ipn };
    float2 zv = { xv.x * ixn, xv.y * ixn };
    float2 Mv = { zw * wv.x, zw * wv.y };
    float2 uv = { (zv.x - Mv.x) * ir1, (zv.y - Mv.y) * ir1 };
    __syncthreads();

    float a0[16], a1[16];
    #pragma unroll
    for (int q = 0; q < 4; ++q) {
        float4 cw = *(const float4*)&CsT[0][q * 4];   // C[r][0] (broadcast)
        float4 cu = *(const float4*)&CsT[1][q * 4];   // C[r][1]
        #pragma unroll
        for (int i = 0; i < 4; ++i) {
            float w_ = ((const float*)&cw)[i], u_ = ((const float*)&cu)[i];
            a0[q * 4 + i] = w_ * wv.x + u_ * uv.x;
            a1[q * 4 + i] = w_ * wv.y + u_ * uv.y;
        }
    }

    const float* rbase = rands + (size_t)j * NEXP * DD;
    #pragma unroll 4
    for (int k = 0; k < NEXP; ++k) {
        float2 rv = ((const float2*)(rbase + (size_t)k * DD))[t];
        #pragma unroll
        for (int q = 0; q < 4; ++q) {
            float4 cc = *(const float4*)&CsT[2 + k][q * 4];  // broadcast b128
            #pragma unroll
            for (int i = 0; i < 4; ++i) {
                float c_ = ((const float*)&cc)[i];
                a0[q * 4 + i] += c_ * rv.x;
                a1[q * 4 + i] += c_ * rv.y;
            }
        }
    }

    float* orow = out + ((size_t)BB + (size_t)j * NEXP) * DD;
    #pragma unroll 4
    for (int r = 0; r < 16; ++r) {
        float2 ov = { Mv.x + r1n * a0[r], Mv.y + r1n * a1[r] };
        ((float2*)(orow + (size_t)r * DD))[t] = ov;
    }

    if (t < NEXP) out[AUGT_OFF + BB + (size_t)j * NEXP + t] = (float)cls;
}

// ---------------------------------------------------------------------------
extern "C" void kernel_launch(void* const* d_in, const int* in_sizes, int n_in,
                              void* d_out, int out_size, void* d_ws, size_t ws_size,
                              hipStream_t stream)
{
    const float* x     = (const float*)d_in[0];   // [8192,512]
    const int*   y     = (const int*)d_in[1];     // [8192]
    const float* prox  = (const float*)d_in[2];   // [11318,512]
    const float* bw    = (const float*)d_in[3];   // [17,17]
    const float* rands = (const float*)d_in[4];   // [2048,16,512]
    float* out = (float*)d_out;

    char* wsb = (char*)d_ws;
    double* scores = (double*)wsb;                            // 64 KB
    int* ranks = (int*)(wsb + 65536);                         // 32 KB
    int* sel   = (int*)(wsb + 65536 + 32768);                 // 8 KB
    float* gbuf = (float*)(wsb + 114688);                     // 2048*1312 B = 2.56 MB
    float* cbuf = (float*)(wsb + 114688 + (size_t)TOPK * GSTRIDE * 4); // 2.25 MB

    hipMemsetAsync(ranks, 0, BB * sizeof(int), stream);

    score_kernel<<<BB, 64, 0, stream>>>(x, y, prox, scores);
    dim3 rgrid(BB / 256, BB / JCHUNK);
    rank_kernel<<<rgrid, 256, 0, stream>>>(scores, ranks);
    compact_kernel<<<1, 256, 0, stream>>>(ranks, sel, out);
    gram_kernel<<<TOPK, 256, 0, stream>>>(x, y, prox, rands, sel, gbuf);
    solve_kernel<<<TOPK / 4, 256, 0, stream>>>(gbuf, bw, cbuf);
    emit_kernel<<<TOPK + COPY_BLOCKS, 256, 0, stream>>>(x, y, prox, rands, sel,
                                                        gbuf, cbuf, out);
}

// Round 12
// 71.974 us; speedup vs baseline: 1.5626x; 1.3166x over previous
//
#include <hip/hip_runtime.h>
#include <math.h>

// Problem constants (from reference)
#define BB     8192      // batch
#define DD     512       // embed dim
#define NEXP   16        // expansions per sample
#define TOPK   2048      // round(B * 0.25)
#define AUGX_ROWS (BB + TOPK * NEXP)              // 40960
#define AUGT_OFF  ((size_t)AUGX_ROWS * DD)        // 20971520
#define ISEXP_OFF (AUGT_OFF + AUGX_ROWS)          // 21012480

#define JCHUNK 256       // j-scores per rank block
#define COPY_BLOCKS 1024 // copy blocks fused into expand launch
#define BMP 520          // bf16 row pitch: 1040 B = 16B-aligned, bank step 4

typedef __attribute__((ext_vector_type(8)))  short bf16x8;
typedef __attribute__((ext_vector_type(16))) float f32x16;

__device__ inline ushort f2bf(float f) {   // RNE f32 -> bf16 bits
    uint u = __builtin_bit_cast(uint, f);
    return (ushort)((u + 0x7FFFu + ((u >> 16) & 1u)) >> 16);
}
__device__ inline float bf2f(ushort b) {
    uint u = ((uint)b) << 16;
    return __builtin_bit_cast(float, u);
}

// ---------------------------------------------------------------------------
// Kernel 1: per-sample score in f64 (matches harness ordering at ties)
__global__ __launch_bounds__(64) void score_kernel(
    const float* __restrict__ x, const int* __restrict__ y,
    const float* __restrict__ prox, double* __restrict__ scores)
{
    int i = blockIdx.x;
    int lane = threadIdx.x;
    const float* xr = x + (size_t)i * DD;
    const float* pr = prox + (size_t)y[i] * DD;
    double sx = 0.0, sp = 0.0, dp = 0.0;
    #pragma unroll
    for (int e = 0; e < DD; e += 64) {
        float xv = xr[e + lane];
        float pv = pr[e + lane];
        sx += (double)xv * (double)xv;
        sp += (double)pv * (double)pv;
        dp += (double)xv * (double)pv;
    }
    #pragma unroll
    for (int off = 32; off > 0; off >>= 1) {
        sx += __shfl_down(sx, off);
        sp += __shfl_down(sp, off);
        dp += __shfl_down(dp, off);
    }
    if (lane == 0) {
        scores[i] = dp / (sqrt(sx + 1e-12) * sqrt(sp + 1e-12));
    }
}

// ---------------------------------------------------------------------------
// Kernel 2: partial rank accumulation; tie-break = jax.lax.top_k stability.
// Integer atomics only (exact, order-independent).
__global__ __launch_bounds__(256) void rank_kernel(
    const double* __restrict__ scores, int* __restrict__ ranks)
{
    __shared__ double ch[JCHUNK];
    int i = blockIdx.x * 256 + threadIdx.x;
    int jbase = blockIdx.y * JCHUNK;
    double si = scores[i];
    if (threadIdx.x < JCHUNK) ch[threadIdx.x] = scores[jbase + threadIdx.x];
    __syncthreads();
    int rank = 0;
    #pragma unroll 8
    for (int j = 0; j < JCHUNK; ++j) {
        double sj = ch[j];
        int jj = jbase + j;
        rank += (sj > si || (sj == si && jj < i)) ? 1 : 0;
    }
    atomicAdd(&ranks[i], rank);
}

// ---------------------------------------------------------------------------
// Kernel 3: ordered compaction (ascending sel[]), write is_expan floats.
__global__ __launch_bounds__(256) void compact_kernel(
    const int* __restrict__ ranks, int* __restrict__ sel, float* __restrict__ out)
{
    __shared__ int wsum[4];
    int t = threadIdx.x;
    int base = t * 32;
    int fl[32];
    int cnt = 0;
    for (int k = 0; k < 32; ++k) {
        fl[k] = (ranks[base + k] < TOPK) ? 1 : 0;
        cnt += fl[k];
    }
    int lane = t & 63, wave = t >> 6;
    int inc = cnt;
    #pragma unroll
    for (int off = 1; off < 64; off <<= 1) {
        int n = __shfl_up(inc, off);
        if (lane >= off) inc += n;
    }
    if (lane == 63) wsum[wave] = inc;
    __syncthreads();
    int wbase = 0;
    for (int w = 0; w < wave; ++w) wbase += wsum[w];
    int pos = wbase + inc - cnt;
    for (int k = 0; k < 32; ++k) {
        int i = base + k;
        out[ISEXP_OFF + i] = fl[k] ? 1.0f : 0.0f;
        if (fl[k]) sel[pos++] = i;
    }
}

// ---------------------------------------------------------------------------
__device__ inline void block_sum3(float& a, float& b, float& c, float* red, int t)
{
    #pragma unroll
    for (int off = 32; off > 0; off >>= 1) {
        a += __shfl_down(a, off);
        b += __shfl_down(b, off);
        c += __shfl_down(c, off);
    }
    __syncthreads();
    if ((t & 63) == 0) { int w = t >> 6; red[w] = a; red[4 + w] = b; red[8 + w] = c; }
    __syncthreads();
    a = red[0] + red[1] + red[2] + red[3];
    b = red[4] + red[5] + red[6] + red[7];
    c = red[8] + red[9] + red[10] + red[11];
}

// ---------------------------------------------------------------------------
// Kernel 5: fused expansion (blocks 0..TOPK-1) + raw-x copy (blocks >= TOPK).
// 4-wave MFMA Gram (deterministic LDS partials) -> wave0 register-sum +
// register right-looking Cholesky (proven in R9-R11 solve_kernel) ->
// back-solve (bwg read direct from global) -> parallel output GEMM from LDS.
__global__ __launch_bounds__(256, 6) void expand_kernel(
    const float* __restrict__ x, const int* __restrict__ y,
    const float* __restrict__ prox, const float* __restrict__ bwg,
    const float* __restrict__ rands, const int* __restrict__ sel,
    float* __restrict__ out)
{
    const int t = threadIdx.x;

    // ---- fused copy blocks: aug_x[0:B] = x, aug_t[0:B] = y
    if (blockIdx.x >= TOPK) {
        int tid = (blockIdx.x - TOPK) * 256 + t;
        const float4* src = (const float4*)x;
        float4* dst = (float4*)out;
        const int nvec = BB * DD / 4;
        for (int idx = tid; idx < nvec; idx += COPY_BLOCKS * 256) dst[idx] = src[idx];
        for (int i = tid; i < BB; i += COPY_BLOCKS * 256) out[AUGT_OFF + i] = (float)y[i];
        return;
    }

    __shared__ ushort Bm[18][BMP];   // bf16 basis rows            18720 B
    __shared__ float Gp[4][18][19];  // per-wave MFMA partials      5472 B
    __shared__ float Ls[18][19];     // Cholesky factor             1368 B
    __shared__ float Cs[16][18];     // output coefficient rows     1152 B
    __shared__ float invd[18];       // 1 / L[k][k]                   72 B
    __shared__ float red[12];        //                               48 B

    const int j = blockIdx.x;
    const int wave = t >> 6, lane = t & 63;
    const int s = sel[j];
    const int cls = y[s];

    // ---- stage 16 rand rows into LDS as bf16 (transient registers only)
    {
        const float* rbase = rands + (size_t)j * NEXP * DD;
        #pragma unroll
        for (int i = 0; i < 8; ++i) {
            int row = 2 * i + (t >> 7);
            int col = (t & 127) * 4;
            float4 vv = *(const float4*)(rbase + (size_t)row * DD + col);
            ushort4 bv = { f2bf(vv.x), f2bf(vv.y), f2bf(vv.z), f2bf(vv.w) };
            *(ushort4*)&Bm[2 + row][col] = bv;
        }
    }

    float2 xv = ((const float2*)(x + (size_t)s * DD))[t];
    float2 pv = ((const float2*)(prox + (size_t)cls * DD))[t];

    float sx  = xv.x * xv.x + xv.y * xv.y;
    float sp  = pv.x * pv.x + pv.y * pv.y;
    float dxp = xv.x * pv.x + xv.y * pv.y;
    block_sum3(sx, sp, dxp, red, t);

    float xn = sqrtf(sx + 1e-12f), pn = sqrtf(sp + 1e-12f);
    float2 z  = { xv.x / xn, xv.y / xn };
    float2 w  = { pv.x / pn, pv.y / pn };
    float zw  = dxp / (xn * pn);
    float2 M  = { zw * w.x, zw * w.y };
    float2 r1 = { z.x - M.x, z.y - M.y };
    float r1sq = fmaxf(1.0f - zw * zw, 1e-12f);  // |r1|^2 = 1 - zw^2 (unit z,w)
    float r1n = sqrtf(r1sq);
    float inv1 = 1.0f / r1n;
    float2 u1 = { r1.x * inv1, r1.y * inv1 };

    { ushort2 wb = { f2bf(w.x),  f2bf(w.y)  }; *(ushort2*)&Bm[0][2 * t] = wb; }
    { ushort2 ub = { f2bf(u1.x), f2bf(u1.y) }; *(ushort2*)&Bm[1][2 * t] = ub; }

    // expansion labels (no dependency on what follows)
    if (t < NEXP) out[AUGT_OFF + BB + (size_t)j * NEXP + t] = (float)cls;
    __syncthreads();   // barrier A: Bm fully staged

    // ---- 4-wave MFMA Gram: wave covers K-slice [wave*128, wave*128+128).
    // A-frag == B-frag (G = B.B^T): lane row = lane&31 (clamped),
    // k = kw + stp*16 + (lane>>5)*8 + i.
    {
        int row = lane & 31; if (row > 17) row = 17;
        int koff = (lane >> 5) * 8;
        const int kw = wave * 128;
        f32x16 acc = {0,0,0,0,0,0,0,0,0,0,0,0,0,0,0,0};
        #pragma unroll
        for (int stp = 0; stp < 8; ++stp) {
            bf16x8 av = *(const bf16x8*)&Bm[row][kw + stp * 16 + koff];
            acc = __builtin_amdgcn_mfma_f32_32x32x16_bf16(av, av, acc, 0, 0, 0);
        }
        // D layout: col = lane&31, row = (reg&3) + 8*(reg>>2) + 4*(lane>>5)
        int col = lane & 31;
        if (col < 18) {
            #pragma unroll
            for (int rg = 0; rg < 16; ++rg) {
                int rr = (rg & 3) + 8 * (rg >> 2) + 4 * (lane >> 5);
                if (rr < 18) Gp[wave][rr][col] = acc[rg];
            }
        }
    }
    __syncthreads();   // barrier B: Gp complete

    // ---- wave 0: register-sum of partials + register right-looking Cholesky
    // (shuffle-broadcast pivots), L -> Ls; then 16 back-solves (bwg global).
    if (wave == 0) {
        const int jl = (lane < 18) ? lane : 17;   // lanes >=18 duplicate row 17
        float Greg[18];
        #pragma unroll
        for (int c = 0; c < 18; ++c)
            Greg[c] = (Gp[0][jl][c] + Gp[1][jl][c])
                    + (Gp[2][jl][c] + Gp[3][jl][c]);

        float Lrow[18], idr[18];
        #pragma unroll
        for (int col = 0; col < 18; ++col) {
            float pivot = __shfl(Greg[col], col);   // fully-updated diagonal
            float rsq = rsqrtf(pivot);
            idr[col] = rsq;
            float lv = (jl >= col) ? Greg[col] * rsq : 0.0f;
            Lrow[col] = lv;
            #pragma unroll
            for (int c = col + 1; c < 18; ++c) {    // Schur update
                float lc = __shfl(lv, c);           // L[c][col]
                Greg[c] -= lv * lc;
            }
        }
        #pragma unroll
        for (int c = 0; c < 18; ++c) Ls[jl][c] = Lrow[c];
        if (lane < 18) invd[lane] = idr[lane];

        // back-substitution on lanes 0..15: solve L^T c = bw_ext_r (r = lane).
        // Same-wave LDS RAW (writes above, cross-lane reads below) is in-order.
        if (lane < 16) {
            float b[18];
            b[0] = 0.0f;
            #pragma unroll
            for (int m = 1; m < 18; ++m) b[m] = bwg[17 + lane * 17 + (m - 1)];
            #pragma unroll
            for (int k = 17; k >= 0; --k) {
                float xk = b[k] * idr[k];
                Cs[lane][k] = xk;
                #pragma unroll
                for (int m = 0; m < k; ++m)
                    b[m] -= Ls[k][m] * xk;          // broadcast reads of row k
            }
        }
    }
    __syncthreads();   // barrier C: Cs ready

    // ---- outputs: out_r = M + r1n * sum_j C[r][j] * b_j, 8-row chunks.
    float* orow = out + ((size_t)BB + (size_t)j * NEXP) * DD;
    #pragma unroll
    for (int half = 0; half < 2; ++half) {
        float acc0[8], acc1[8];
        #pragma unroll
        for (int r = 0; r < 8; ++r) { acc0[r] = 0.0f; acc1[r] = 0.0f; }
        #pragma unroll
        for (int jj = 0; jj < 18; ++jj) {
            float bx = bf2f(Bm[jj][2 * t]);
            float by = bf2f(Bm[jj][2 * t + 1]);
            #pragma unroll
            for (int r = 0; r < 8; ++r) {
                float cc = Cs[half * 8 + r][jj];  // broadcast read
                acc0[r] += cc * bx;
                acc1[r] += cc * by;
            }
        }
        #pragma unroll
        for (int r = 0; r < 8; ++r) {
            float2 ov = { M.x + r1n * acc0[r], M.y + r1n * acc1[r] };
            ((float2*)(orow + (size_t)(half * 8 + r) * DD))[t] = ov;
        }
    }
}

// ---------------------------------------------------------------------------
extern "C" void kernel_launch(void* const* d_in, const int* in_sizes, int n_in,
                              void* d_out, int out_size, void* d_ws, size_t ws_size,
                              hipStream_t stream)
{
    const float* x     = (const float*)d_in[0];   // [8192,512]
    const int*   y     = (const int*)d_in[1];     // [8192]
    const float* prox  = (const float*)d_in[2];   // [11318,512]
    const float* bw    = (const float*)d_in[3];   // [17,17]
    const float* rands = (const float*)d_in[4];   // [2048,16,512]
    float* out = (float*)d_out;

    char* wsb = (char*)d_ws;
    double* scores = (double*)wsb;                            // 64 KB
    int* ranks = (int*)(wsb + 65536);                         // 32 KB
    int* sel   = (int*)(wsb + 65536 + 32768);                 // 8 KB

    hipMemsetAsync(ranks, 0, BB * sizeof(int), stream);

    score_kernel<<<BB, 64, 0, stream>>>(x, y, prox, scores);
    dim3 rgrid(BB / 256, BB / JCHUNK);
    rank_kernel<<<rgrid, 256, 0, stream>>>(scores, ranks);
    compact_kernel<<<1, 256, 0, stream>>>(ranks, sel, out);
    expand_kernel<<<TOPK + COPY_BLOCKS, 256, 0, stream>>>(x, y, prox, bw, rands, sel, out);
}